// Round 6
// baseline (477.375 us; speedup 1.0000x reference)
//
#include <hip/hip_runtime.h>
#include <math.h>

#define N_NODES 20000
#define N_EDGES 320000
#define EMB 256
#define NUM_TILES ((N_NODES + 255) / 256)  // 79
#define LDS_PITCH 264                      // 256 + 8 shorts: breaks bank-stride, keeps 16B align

typedef __attribute__((ext_vector_type(8))) short short8;
typedef __attribute__((ext_vector_type(4))) float floatx4;

__device__ __forceinline__ unsigned short bf16r(float x) {
    unsigned u = __float_as_uint(x);
    u += 0x7fffu + ((u >> 16) & 1u);
    return (unsigned short)(u >> 16);
}

// ---------- prep: count degrees + convert W_self to bf16 ----------
__global__ __launch_bounds__(256) void prep_kernel(
        const float* __restrict__ W, const int* __restrict__ dst,
        int* __restrict__ deg, unsigned short* __restrict__ Wb) {
    int gid = blockIdx.x * 256 + threadIdx.x;
    if (gid < N_EDGES) atomicAdd(&deg[dst[gid]], 1);
    if (gid < (EMB * EMB) / 8) {
        long off = (long)gid * 8;
        float4 x = *(const float4*)(W + off);
        float4 y = *(const float4*)(W + off + 4);
        uint4 o;
        o.x = (unsigned)bf16r(x.x) | ((unsigned)bf16r(x.y) << 16);
        o.y = (unsigned)bf16r(x.z) | ((unsigned)bf16r(x.w) << 16);
        o.z = (unsigned)bf16r(y.x) | ((unsigned)bf16r(y.y) << 16);
        o.w = (unsigned)bf16r(y.z) | ((unsigned)bf16r(y.w) << 16);
        *(uint4*)(Wb + off) = o;
    }
}

// ---------- CSR: fused scan (block b computes its own base by summing prior tiles) ----------
__global__ __launch_bounds__(256) void csr_kernel(const int* __restrict__ deg,
                                                  int* __restrict__ row_start,
                                                  int* __restrict__ cursor) {
    __shared__ int red[256];
    __shared__ int sc[256];
    int b = blockIdx.x, t = threadIdx.x;
    int i = b * 256 + t;
    int v = (i < N_NODES) ? deg[i] : 0;
    // base = sum of deg[0 .. b*256)
    int s = 0;
    for (int j = t; j < b * 256; j += 256) s += deg[j];
    red[t] = s;
    sc[t] = v;
    __syncthreads();
#pragma unroll
    for (int off = 128; off > 0; off >>= 1) {
        if (t < off) red[t] += red[t + off];
        __syncthreads();
    }
    int base = red[0];
    // Hillis-Steele inclusive scan of own tile
#pragma unroll
    for (int off = 1; off < 256; off <<= 1) {
        int tmp = (t >= off) ? sc[t - off] : 0;
        __syncthreads();
        sc[t] += tmp;
        __syncthreads();
    }
    int excl = base + sc[t] - v;
    if (i < N_NODES) {
        row_start[i] = excl;
        cursor[i] = excl;
    }
    if (i == N_NODES - 1) row_start[N_NODES] = excl + v;
}

__global__ void scatter_kernel(const int* __restrict__ src, const int* __restrict__ dst,
                               int* __restrict__ cursor, int* __restrict__ csr_src, int n) {
    int i = blockIdx.x * blockDim.x + threadIdx.x;
    if (i < n) {
        int d = dst[i];
        int pos = atomicAdd(&cursor[d], 1);
        csr_src[pos] = src[i];
    }
}

// ---------- MFMA GEMM: S = h @ W_self^T ; packed[n][c] = (bf16(exp(S)), bf16(h)) ----------
__global__ __launch_bounds__(256) void gemm_kernel(
        const float* __restrict__ h, const unsigned short* __restrict__ Wb,
        unsigned int* __restrict__ packed) {
    __shared__ unsigned short At[32][LDS_PITCH];  // bf16(h) tile
    __shared__ unsigned short Et[32][LDS_PITCH];  // bf16(exp(S)) tile
    int tid = threadIdx.x;
    int w = tid >> 6, l = tid & 63;
    int m0 = blockIdx.x * 32;
    int n0 = w * 64;
    int lm = l & 15, lk = (l >> 4) * 8;

    // stage A: 32 rows x 256 cols fp32 -> bf16 LDS, coalesced float4 reads
#pragma unroll
    for (int it = 0; it < 8; ++it) {
        int q = it * 256 + tid;          // [0, 2048)
        int row = q >> 6;
        int c4 = (q & 63) * 4;
        float4 x = *(const float4*)(h + (size_t)(m0 + row) * EMB + c4);
        At[row][c4 + 0] = bf16r(x.x);
        At[row][c4 + 1] = bf16r(x.y);
        At[row][c4 + 2] = bf16r(x.z);
        At[row][c4 + 3] = bf16r(x.w);
    }
    __syncthreads();

    floatx4 acc[2][4];
#pragma unroll
    for (int mt = 0; mt < 2; ++mt)
#pragma unroll
        for (int nt = 0; nt < 4; ++nt) acc[mt][nt] = (floatx4){0.f, 0.f, 0.f, 0.f};

    const unsigned short* a0p = &At[lm][lk];
    const unsigned short* a1p = &At[16 + lm][lk];
    const unsigned short* bp = Wb + (size_t)(n0 + lm) * EMB + lk;

#pragma unroll
    for (int k0 = 0; k0 < EMB; k0 += 32) {
        short8 a0 = *(const short8*)(a0p + k0);
        short8 a1 = *(const short8*)(a1p + k0);
        short8 b0 = *(const short8*)(bp + k0);
        short8 b1 = *(const short8*)(bp + 16 * EMB + k0);
        short8 b2 = *(const short8*)(bp + 32 * EMB + k0);
        short8 b3 = *(const short8*)(bp + 48 * EMB + k0);
        acc[0][0] = __builtin_amdgcn_mfma_f32_16x16x32_bf16(a0, b0, acc[0][0], 0, 0, 0);
        acc[0][1] = __builtin_amdgcn_mfma_f32_16x16x32_bf16(a0, b1, acc[0][1], 0, 0, 0);
        acc[0][2] = __builtin_amdgcn_mfma_f32_16x16x32_bf16(a0, b2, acc[0][2], 0, 0, 0);
        acc[0][3] = __builtin_amdgcn_mfma_f32_16x16x32_bf16(a0, b3, acc[0][3], 0, 0, 0);
        acc[1][0] = __builtin_amdgcn_mfma_f32_16x16x32_bf16(a1, b0, acc[1][0], 0, 0, 0);
        acc[1][1] = __builtin_amdgcn_mfma_f32_16x16x32_bf16(a1, b1, acc[1][1], 0, 0, 0);
        acc[1][2] = __builtin_amdgcn_mfma_f32_16x16x32_bf16(a1, b2, acc[1][2], 0, 0, 0);
        acc[1][3] = __builtin_amdgcn_mfma_f32_16x16x32_bf16(a1, b3, acc[1][3], 0, 0, 0);
    }

    // E -> LDS in C/D layout (col = lane&15, row = (lane>>4)*4 + reg)
#pragma unroll
    for (int mt = 0; mt < 2; ++mt)
#pragma unroll
        for (int nt = 0; nt < 4; ++nt) {
            int col = n0 + nt * 16 + lm;
#pragma unroll
            for (int r = 0; r < 4; ++r) {
                int row = mt * 16 + (l >> 4) * 4 + r;
                Et[row][col] = bf16r(__expf(acc[mt][nt][r]));
            }
        }
    __syncthreads();

    // pack & store: fully coalesced uint4 stores
#pragma unroll
    for (int it = 0; it < 8; ++it) {
        int q = it * 256 + tid;
        int row = q >> 6;
        int c4 = (q & 63) * 4;
        uint4 o;
        o.x = (unsigned)Et[row][c4 + 0] | ((unsigned)At[row][c4 + 0] << 16);
        o.y = (unsigned)Et[row][c4 + 1] | ((unsigned)At[row][c4 + 1] << 16);
        o.z = (unsigned)Et[row][c4 + 2] | ((unsigned)At[row][c4 + 2] << 16);
        o.w = (unsigned)Et[row][c4 + 3] | ((unsigned)At[row][c4 + 3] << 16);
        *(uint4*)&packed[(size_t)(m0 + row) * EMB + c4] = o;
    }
}

// ---------- aggregate: dynamic per-wave node assignment (ticket counter) ----------
#define PROC(p)                                                                  \
    {                                                                            \
        unsigned u;                                                              \
        float e, hv;                                                             \
        u = (p).x; e = __uint_as_float(u << 16);                                 \
        hv = __uint_as_float(u & 0xffff0000u); ss0 += e; a0 = fmaf(e, hv, a0);   \
        u = (p).y; e = __uint_as_float(u << 16);                                 \
        hv = __uint_as_float(u & 0xffff0000u); ss1 += e; a1 = fmaf(e, hv, a1);   \
        u = (p).z; e = __uint_as_float(u << 16);                                 \
        hv = __uint_as_float(u & 0xffff0000u); ss2 += e; a2 = fmaf(e, hv, a2);   \
        u = (p).w; e = __uint_as_float(u << 16);                                 \
        hv = __uint_as_float(u & 0xffff0000u); ss3 += e; a3 = fmaf(e, hv, a3);   \
    }

__global__ __launch_bounds__(256) void aggregate_kernel(
        const float* __restrict__ h, const uint4* __restrict__ packed,
        const int* __restrict__ row_start, const int* __restrict__ csr_src,
        int* __restrict__ counter, float* __restrict__ out) {
    int l = threadIdx.x & 63;
    for (;;) {
        int node = 0;
        if (l == 0) node = atomicAdd(counter, 1);
        node = __shfl(node, 0);
        if (node >= N_NODES) return;
        int start = row_start[node], end = row_start[node + 1];
        if (start == end) {  // zero in-degree: pass through h
            float4 v = *(const float4*)(h + (size_t)node * EMB + l * 4);
            *(float4*)(out + (size_t)node * EMB + l * 4) = v;
            continue;
        }
        float ss0 = 0.f, ss1 = 0.f, ss2 = 0.f, ss3 = 0.f;
        float a0 = 0.f, a1 = 0.f, a2 = 0.f, a3 = 0.f;
        for (int base = start; base < end; base += 64) {
            int cnt = min(64, end - base);
            int sv = (l < cnt) ? csr_src[base + l] : 0;
            int i = 0;
            for (; i + 8 <= cnt; i += 8) {
                int s0 = __shfl(sv, i),     s1 = __shfl(sv, i + 1);
                int s2 = __shfl(sv, i + 2), s3 = __shfl(sv, i + 3);
                int s4 = __shfl(sv, i + 4), s5 = __shfl(sv, i + 5);
                int s6 = __shfl(sv, i + 6), s7 = __shfl(sv, i + 7);
                uint4 p0 = packed[(size_t)s0 * 64 + l];
                uint4 p1 = packed[(size_t)s1 * 64 + l];
                uint4 p2 = packed[(size_t)s2 * 64 + l];
                uint4 p3 = packed[(size_t)s3 * 64 + l];
                uint4 p4 = packed[(size_t)s4 * 64 + l];
                uint4 p5 = packed[(size_t)s5 * 64 + l];
                uint4 p6 = packed[(size_t)s6 * 64 + l];
                uint4 p7 = packed[(size_t)s7 * 64 + l];
                PROC(p0); PROC(p1); PROC(p2); PROC(p3);
                PROC(p4); PROC(p5); PROC(p6); PROC(p7);
            }
            for (; i < cnt; ++i) {
                int s = __shfl(sv, i);
                uint4 p = packed[(size_t)s * 64 + l];
                PROC(p);
            }
        }
        float4 o;
        o.x = a0 / ss0; o.y = a1 / ss1; o.z = a2 / ss2; o.w = a3 / ss3;
        *(float4*)(out + (size_t)node * EMB + l * 4) = o;
    }
}

// ---------- launch ----------
extern "C" void kernel_launch(void* const* d_in, const int* in_sizes, int n_in,
                              void* d_out, int out_size, void* d_ws, size_t ws_size,
                              hipStream_t stream) {
    const float* h      = (const float*)d_in[0];
    // W_nb (d_in[1]), b_nb (d_in[2]), b_self (d_in[4]) are mathematically
    // irrelevant: constant per (dst, channel) inside each softmax segment,
    // cancel exactly in alpha = e / seg_sum.
    const float* W_self = (const float*)d_in[3];
    const int*   src    = (const int*)d_in[5];
    const int*   dst    = (const int*)d_in[6];
    float* out = (float*)d_out;

    char* ws = (char*)d_ws;
    unsigned int* packed = (unsigned int*)ws;                 // [N,256] uint (E,h) pairs
    size_t off = (size_t)N_NODES * EMB * sizeof(unsigned int);
    unsigned short* Wb = (unsigned short*)(ws + off); off += (size_t)EMB * EMB * sizeof(unsigned short);
    int* deg       = (int*)(ws + off); off += (size_t)N_NODES * sizeof(int);
    int* counter   = (int*)(ws + off); off += sizeof(int);    // adjacent to deg: one memset covers both
    int* row_start = (int*)(ws + off); off += (size_t)(N_NODES + 1) * sizeof(int);
    int* cursor    = (int*)(ws + off); off += (size_t)N_NODES * sizeof(int);
    int* csr_src   = (int*)(ws + off); off += (size_t)N_EDGES * sizeof(int);

    (void)hipMemsetAsync(deg, 0, ((size_t)N_NODES + 1) * sizeof(int), stream);

    prep_kernel<<<(N_EDGES + 255) / 256, 256, 0, stream>>>(W_self, dst, deg, Wb);
    csr_kernel<<<NUM_TILES, 256, 0, stream>>>(deg, row_start, cursor);
    scatter_kernel<<<(N_EDGES + 255) / 256, 256, 0, stream>>>(src, dst, cursor, csr_src, N_EDGES);
    gemm_kernel<<<N_NODES / 32, 256, 0, stream>>>(h, Wb, packed);
    aggregate_kernel<<<2048, 256, 0, stream>>>(h, (const uint4*)packed, row_start, csr_src,
                                               counter, out);
}

// Round 7
// 280.537 us; speedup vs baseline: 1.7016x; 1.7016x over previous
//
#include <hip/hip_runtime.h>
#include <math.h>

#define N_NODES 20000
#define N_EDGES 320000
#define EMB 256
#define NUM_TILES ((N_NODES + 255) / 256)  // 79
#define LDS_PITCH 264                      // 256 + 8 shorts: breaks bank-stride, keeps 16B align

typedef __attribute__((ext_vector_type(8))) short short8;
typedef __attribute__((ext_vector_type(4))) float floatx4;

__device__ __forceinline__ unsigned short bf16r(float x) {
    unsigned u = __float_as_uint(x);
    u += 0x7fffu + ((u >> 16) & 1u);
    return (unsigned short)(u >> 16);
}

// ---------- prep: count degrees + convert W_self to bf16 ----------
__global__ __launch_bounds__(256) void prep_kernel(
        const float* __restrict__ W, const int* __restrict__ dst,
        int* __restrict__ deg, unsigned short* __restrict__ Wb) {
    int gid = blockIdx.x * 256 + threadIdx.x;
    if (gid < N_EDGES) atomicAdd(&deg[dst[gid]], 1);
    if (gid < (EMB * EMB) / 8) {
        long off = (long)gid * 8;
        float4 x = *(const float4*)(W + off);
        float4 y = *(const float4*)(W + off + 4);
        uint4 o;
        o.x = (unsigned)bf16r(x.x) | ((unsigned)bf16r(x.y) << 16);
        o.y = (unsigned)bf16r(x.z) | ((unsigned)bf16r(x.w) << 16);
        o.z = (unsigned)bf16r(y.x) | ((unsigned)bf16r(y.y) << 16);
        o.w = (unsigned)bf16r(y.z) | ((unsigned)bf16r(y.w) << 16);
        *(uint4*)(Wb + off) = o;
    }
}

// ---------- CSR: fused scan; also histogram degrees (descending-order key) ----------
__global__ __launch_bounds__(256) void csr_kernel(const int* __restrict__ deg,
                                                  int* __restrict__ row_start,
                                                  int* __restrict__ cursor,
                                                  int* __restrict__ hist) {
    __shared__ int red[256];
    __shared__ int sc[256];
    int b = blockIdx.x, t = threadIdx.x;
    int i = b * 256 + t;
    int v = (i < N_NODES) ? deg[i] : 0;
    // base = sum of deg[0 .. b*256)
    int s = 0;
    for (int j = t; j < b * 256; j += 256) s += deg[j];
    red[t] = s;
    sc[t] = v;
    __syncthreads();
#pragma unroll
    for (int off = 128; off > 0; off >>= 1) {
        if (t < off) red[t] += red[t + off];
        __syncthreads();
    }
    int base = red[0];
#pragma unroll
    for (int off = 1; off < 256; off <<= 1) {
        int tmp = (t >= off) ? sc[t - off] : 0;
        __syncthreads();
        sc[t] += tmp;
        __syncthreads();
    }
    int excl = base + sc[t] - v;
    if (i < N_NODES) {
        row_start[i] = excl;
        cursor[i] = excl;
        atomicAdd(&hist[255 - min(v, 255)], 1);  // key: descending degree
    }
    if (i == N_NODES - 1) row_start[N_NODES] = excl + v;
}

// ---------- 1-block exclusive scan of hist[256] -> hcur ----------
__global__ __launch_bounds__(256) void hscan_kernel(const int* __restrict__ hist,
                                                    int* __restrict__ hcur) {
    __shared__ int sc[256];
    int t = threadIdx.x;
    int v = hist[t];
    sc[t] = v;
    __syncthreads();
#pragma unroll
    for (int off = 1; off < 256; off <<= 1) {
        int tmp = (t >= off) ? sc[t - off] : 0;
        __syncthreads();
        sc[t] += tmp;
        __syncthreads();
    }
    hcur[t] = sc[t] - v;  // exclusive
}

// ---------- scatter edges into CSR + scatter nodes into degree-sorted perm ----------
__global__ void scatter_kernel(const int* __restrict__ src, const int* __restrict__ dst,
                               int* __restrict__ cursor, int* __restrict__ csr_src,
                               const int* __restrict__ deg, int* __restrict__ hcur,
                               int* __restrict__ perm, int n) {
    int i = blockIdx.x * blockDim.x + threadIdx.x;
    if (i < n) {
        int d = dst[i];
        int pos = atomicAdd(&cursor[d], 1);
        csr_src[pos] = src[i];
    }
    if (i < N_NODES) {
        int key = 255 - min(deg[i], 255);
        int pos = atomicAdd(&hcur[key], 1);
        perm[pos] = i;
    }
}

// ---------- MFMA GEMM: S = h @ W_self^T ; packed[n][c] = (bf16(exp(S)), bf16(h)) ----------
__global__ __launch_bounds__(256) void gemm_kernel(
        const float* __restrict__ h, const unsigned short* __restrict__ Wb,
        unsigned int* __restrict__ packed) {
    __shared__ unsigned short At[32][LDS_PITCH];  // bf16(h) tile
    __shared__ unsigned short Et[32][LDS_PITCH];  // bf16(exp(S)) tile
    int tid = threadIdx.x;
    int w = tid >> 6, l = tid & 63;
    int m0 = blockIdx.x * 32;
    int n0 = w * 64;
    int lm = l & 15, lk = (l >> 4) * 8;

#pragma unroll
    for (int it = 0; it < 8; ++it) {
        int q = it * 256 + tid;
        int row = q >> 6;
        int c4 = (q & 63) * 4;
        float4 x = *(const float4*)(h + (size_t)(m0 + row) * EMB + c4);
        At[row][c4 + 0] = bf16r(x.x);
        At[row][c4 + 1] = bf16r(x.y);
        At[row][c4 + 2] = bf16r(x.z);
        At[row][c4 + 3] = bf16r(x.w);
    }
    __syncthreads();

    floatx4 acc[2][4];
#pragma unroll
    for (int mt = 0; mt < 2; ++mt)
#pragma unroll
        for (int nt = 0; nt < 4; ++nt) acc[mt][nt] = (floatx4){0.f, 0.f, 0.f, 0.f};

    const unsigned short* a0p = &At[lm][lk];
    const unsigned short* a1p = &At[16 + lm][lk];
    const unsigned short* bp = Wb + (size_t)(n0 + lm) * EMB + lk;

#pragma unroll
    for (int k0 = 0; k0 < EMB; k0 += 32) {
        short8 a0 = *(const short8*)(a0p + k0);
        short8 a1 = *(const short8*)(a1p + k0);
        short8 b0 = *(const short8*)(bp + k0);
        short8 b1 = *(const short8*)(bp + 16 * EMB + k0);
        short8 b2 = *(const short8*)(bp + 32 * EMB + k0);
        short8 b3 = *(const short8*)(bp + 48 * EMB + k0);
        acc[0][0] = __builtin_amdgcn_mfma_f32_16x16x32_bf16(a0, b0, acc[0][0], 0, 0, 0);
        acc[0][1] = __builtin_amdgcn_mfma_f32_16x16x32_bf16(a0, b1, acc[0][1], 0, 0, 0);
        acc[0][2] = __builtin_amdgcn_mfma_f32_16x16x32_bf16(a0, b2, acc[0][2], 0, 0, 0);
        acc[0][3] = __builtin_amdgcn_mfma_f32_16x16x32_bf16(a0, b3, acc[0][3], 0, 0, 0);
        acc[1][0] = __builtin_amdgcn_mfma_f32_16x16x32_bf16(a1, b0, acc[1][0], 0, 0, 0);
        acc[1][1] = __builtin_amdgcn_mfma_f32_16x16x32_bf16(a1, b1, acc[1][1], 0, 0, 0);
        acc[1][2] = __builtin_amdgcn_mfma_f32_16x16x32_bf16(a1, b2, acc[1][2], 0, 0, 0);
        acc[1][3] = __builtin_amdgcn_mfma_f32_16x16x32_bf16(a1, b3, acc[1][3], 0, 0, 0);
    }

    // E -> LDS in C/D layout (col = lane&15, row = (lane>>4)*4 + reg)
#pragma unroll
    for (int mt = 0; mt < 2; ++mt)
#pragma unroll
        for (int nt = 0; nt < 4; ++nt) {
            int col = n0 + nt * 16 + lm;
#pragma unroll
            for (int r = 0; r < 4; ++r) {
                int row = mt * 16 + (l >> 4) * 4 + r;
                Et[row][col] = bf16r(__expf(acc[mt][nt][r]));
            }
        }
    __syncthreads();

#pragma unroll
    for (int it = 0; it < 8; ++it) {
        int q = it * 256 + tid;
        int row = q >> 6;
        int c4 = (q & 63) * 4;
        uint4 o;
        o.x = (unsigned)Et[row][c4 + 0] | ((unsigned)At[row][c4 + 0] << 16);
        o.y = (unsigned)Et[row][c4 + 1] | ((unsigned)At[row][c4 + 1] << 16);
        o.z = (unsigned)Et[row][c4 + 2] | ((unsigned)At[row][c4 + 2] << 16);
        o.w = (unsigned)Et[row][c4 + 3] | ((unsigned)At[row][c4 + 3] << 16);
        *(uint4*)&packed[(size_t)(m0 + row) * EMB + c4] = o;
    }
}

// ---------- aggregate: one wave per node, degree-sorted static schedule ----------
#define PROC(p)                                                                  \
    {                                                                            \
        unsigned u;                                                              \
        float e, hv;                                                             \
        u = (p).x; e = __uint_as_float(u << 16);                                 \
        hv = __uint_as_float(u & 0xffff0000u); ss0 += e; a0 = fmaf(e, hv, a0);   \
        u = (p).y; e = __uint_as_float(u << 16);                                 \
        hv = __uint_as_float(u & 0xffff0000u); ss1 += e; a1 = fmaf(e, hv, a1);   \
        u = (p).z; e = __uint_as_float(u << 16);                                 \
        hv = __uint_as_float(u & 0xffff0000u); ss2 += e; a2 = fmaf(e, hv, a2);   \
        u = (p).w; e = __uint_as_float(u << 16);                                 \
        hv = __uint_as_float(u & 0xffff0000u); ss3 += e; a3 = fmaf(e, hv, a3);   \
    }

__global__ __launch_bounds__(256) void aggregate_kernel(
        const float* __restrict__ h, const uint4* __restrict__ packed,
        const int* __restrict__ row_start, const int* __restrict__ csr_src,
        const int* __restrict__ perm, float* __restrict__ out) {
    int w = threadIdx.x >> 6, l = threadIdx.x & 63;
    int node = perm[blockIdx.x * 4 + w];
    int start = row_start[node], end = row_start[node + 1];
    if (start == end) {  // zero in-degree: pass through h
        float4 v = *(const float4*)(h + (size_t)node * EMB + l * 4);
        *(float4*)(out + (size_t)node * EMB + l * 4) = v;
        return;
    }
    float ss0 = 0.f, ss1 = 0.f, ss2 = 0.f, ss3 = 0.f;
    float a0 = 0.f, a1 = 0.f, a2 = 0.f, a3 = 0.f;
    for (int base = start; base < end; base += 64) {
        int cnt = min(64, end - base);
        int sv = (l < cnt) ? csr_src[base + l] : 0;
        int i = 0;
        for (; i + 8 <= cnt; i += 8) {
            int s0 = __shfl(sv, i),     s1 = __shfl(sv, i + 1);
            int s2 = __shfl(sv, i + 2), s3 = __shfl(sv, i + 3);
            int s4 = __shfl(sv, i + 4), s5 = __shfl(sv, i + 5);
            int s6 = __shfl(sv, i + 6), s7 = __shfl(sv, i + 7);
            uint4 p0 = packed[(size_t)s0 * 64 + l];
            uint4 p1 = packed[(size_t)s1 * 64 + l];
            uint4 p2 = packed[(size_t)s2 * 64 + l];
            uint4 p3 = packed[(size_t)s3 * 64 + l];
            uint4 p4 = packed[(size_t)s4 * 64 + l];
            uint4 p5 = packed[(size_t)s5 * 64 + l];
            uint4 p6 = packed[(size_t)s6 * 64 + l];
            uint4 p7 = packed[(size_t)s7 * 64 + l];
            PROC(p0); PROC(p1); PROC(p2); PROC(p3);
            PROC(p4); PROC(p5); PROC(p6); PROC(p7);
        }
        for (; i + 4 <= cnt; i += 4) {
            int s0 = __shfl(sv, i),     s1 = __shfl(sv, i + 1);
            int s2 = __shfl(sv, i + 2), s3 = __shfl(sv, i + 3);
            uint4 p0 = packed[(size_t)s0 * 64 + l];
            uint4 p1 = packed[(size_t)s1 * 64 + l];
            uint4 p2 = packed[(size_t)s2 * 64 + l];
            uint4 p3 = packed[(size_t)s3 * 64 + l];
            PROC(p0); PROC(p1); PROC(p2); PROC(p3);
        }
        for (; i < cnt; ++i) {
            int s = __shfl(sv, i);
            uint4 p = packed[(size_t)s * 64 + l];
            PROC(p);
        }
    }
    float4 o;
    o.x = a0 / ss0; o.y = a1 / ss1; o.z = a2 / ss2; o.w = a3 / ss3;
    *(float4*)(out + (size_t)node * EMB + l * 4) = o;
}

// ---------- launch ----------
extern "C" void kernel_launch(void* const* d_in, const int* in_sizes, int n_in,
                              void* d_out, int out_size, void* d_ws, size_t ws_size,
                              hipStream_t stream) {
    const float* h      = (const float*)d_in[0];
    // W_nb (d_in[1]), b_nb (d_in[2]), b_self (d_in[4]) are mathematically
    // irrelevant: constant per (dst, channel) inside each softmax segment,
    // cancel exactly in alpha = e / seg_sum.
    const float* W_self = (const float*)d_in[3];
    const int*   src    = (const int*)d_in[5];
    const int*   dst    = (const int*)d_in[6];
    float* out = (float*)d_out;

    char* ws = (char*)d_ws;
    unsigned int* packed = (unsigned int*)ws;                 // [N,256] uint (E,h) pairs
    size_t off = (size_t)N_NODES * EMB * sizeof(unsigned int);
    unsigned short* Wb = (unsigned short*)(ws + off); off += (size_t)EMB * EMB * sizeof(unsigned short);
    int* deg       = (int*)(ws + off); off += (size_t)N_NODES * sizeof(int);
    int* hist      = (int*)(ws + off); off += 256 * sizeof(int);  // adjacent: one memset covers deg+hist
    int* hcur      = (int*)(ws + off); off += 256 * sizeof(int);
    int* row_start = (int*)(ws + off); off += (size_t)(N_NODES + 1) * sizeof(int);
    int* cursor    = (int*)(ws + off); off += (size_t)N_NODES * sizeof(int);
    int* perm      = (int*)(ws + off); off += (size_t)N_NODES * sizeof(int);
    int* csr_src   = (int*)(ws + off); off += (size_t)N_EDGES * sizeof(int);

    (void)hipMemsetAsync(deg, 0, ((size_t)N_NODES + 256) * sizeof(int), stream);

    prep_kernel<<<(N_EDGES + 255) / 256, 256, 0, stream>>>(W_self, dst, deg, Wb);
    csr_kernel<<<NUM_TILES, 256, 0, stream>>>(deg, row_start, cursor, hist);
    hscan_kernel<<<1, 256, 0, stream>>>(hist, hcur);
    scatter_kernel<<<(N_EDGES + 255) / 256, 256, 0, stream>>>(src, dst, cursor, csr_src,
                                                              deg, hcur, perm, N_EDGES);
    gemm_kernel<<<N_NODES / 32, 256, 0, stream>>>(h, Wb, packed);
    aggregate_kernel<<<N_NODES / 4, 256, 0, stream>>>(h, (const uint4*)packed, row_start,
                                                      csr_src, perm, out);
}

// Round 8
// 190.922 us; speedup vs baseline: 2.5004x; 1.4694x over previous
//
#include <hip/hip_runtime.h>
#include <math.h>

#define N_NODES 20000
#define N_EDGES 320000
#define EMB 256
#define NUM_TILES ((N_NODES + 255) / 256)  // 79
#define LDS_PITCH 264                      // 256 + 8 shorts: breaks bank-stride, keeps 16B align

typedef __attribute__((ext_vector_type(8))) short short8;
typedef __attribute__((ext_vector_type(4))) float floatx4;

__device__ __forceinline__ unsigned short bf16r(float x) {
    unsigned u = __float_as_uint(x);
    u += 0x7fffu + ((u >> 16) & 1u);
    return (unsigned short)(u >> 16);
}

// ---------- prep: count degrees + convert W_self to bf16 ----------
__global__ __launch_bounds__(256) void prep_kernel(
        const float* __restrict__ W, const int* __restrict__ dst,
        int* __restrict__ deg, unsigned short* __restrict__ Wb) {
    int gid = blockIdx.x * 256 + threadIdx.x;
    if (gid < N_EDGES) atomicAdd(&deg[dst[gid]], 1);
    if (gid < (EMB * EMB) / 8) {
        long off = (long)gid * 8;
        float4 x = *(const float4*)(W + off);
        float4 y = *(const float4*)(W + off + 4);
        uint4 o;
        o.x = (unsigned)bf16r(x.x) | ((unsigned)bf16r(x.y) << 16);
        o.y = (unsigned)bf16r(x.z) | ((unsigned)bf16r(x.w) << 16);
        o.z = (unsigned)bf16r(y.x) | ((unsigned)bf16r(y.y) << 16);
        o.w = (unsigned)bf16r(y.z) | ((unsigned)bf16r(y.w) << 16);
        *(uint4*)(Wb + off) = o;
    }
}

// ---------- CSR scan + LDS-aggregated degree histogram (descending key) ----------
__global__ __launch_bounds__(256) void csr_kernel(const int* __restrict__ deg,
                                                  int* __restrict__ row_start,
                                                  int* __restrict__ cursor,
                                                  int* __restrict__ hist) {
    __shared__ int red[256];
    __shared__ int sc[256];
    __shared__ int lh[256];
    int b = blockIdx.x, t = threadIdx.x;
    int i = b * 256 + t;
    int v = (i < N_NODES) ? deg[i] : 0;
    int s = 0;
    for (int j = t; j < b * 256; j += 256) s += deg[j];
    red[t] = s;
    sc[t] = v;
    lh[t] = 0;
    __syncthreads();
    if (i < N_NODES) atomicAdd(&lh[255 - min(v, 255)], 1);  // LDS atomic: cheap
#pragma unroll
    for (int off = 128; off > 0; off >>= 1) {
        if (t < off) red[t] += red[t + off];
        __syncthreads();
    }
    int base = red[0];
#pragma unroll
    for (int off = 1; off < 256; off <<= 1) {
        int tmp = (t >= off) ? sc[t - off] : 0;
        __syncthreads();
        sc[t] += tmp;
        __syncthreads();
    }
    int excl = base + sc[t] - v;
    if (i < N_NODES) {
        row_start[i] = excl;
        cursor[i] = excl;
    }
    if (i == N_NODES - 1) row_start[N_NODES] = excl + v;
    if (lh[t] > 0) atomicAdd(&hist[t], lh[t]);  // one global atomic per nonzero bin per block
}

// ---------- 1-block exclusive scan of hist[256] -> hcur ----------
__global__ __launch_bounds__(256) void hscan_kernel(const int* __restrict__ hist,
                                                    int* __restrict__ hcur) {
    __shared__ int sc[256];
    int t = threadIdx.x;
    int v = hist[t];
    sc[t] = v;
    __syncthreads();
#pragma unroll
    for (int off = 1; off < 256; off <<= 1) {
        int tmp = (t >= off) ? sc[t - off] : 0;
        __syncthreads();
        sc[t] += tmp;
        __syncthreads();
    }
    hcur[t] = sc[t] - v;  // exclusive
}

// ---------- perm build: LDS two-pass rank, one global atomic per (block, bin) ----------
__global__ __launch_bounds__(256) void perm_kernel(const int* __restrict__ deg,
                                                   int* __restrict__ hcur,
                                                   int* __restrict__ perm) {
    __shared__ int lcnt[256];
    __shared__ int gbase[256];
    int t = threadIdx.x;
    int i = blockIdx.x * 256 + t;
    lcnt[t] = 0;
    __syncthreads();
    int key = 0, r = 0;
    bool ok = i < N_NODES;
    if (ok) {
        key = 255 - min(deg[i], 255);
        r = atomicAdd(&lcnt[key], 1);   // LDS: within-block rank
    }
    __syncthreads();
    if (lcnt[t] > 0) gbase[t] = atomicAdd(&hcur[t], lcnt[t]);
    __syncthreads();
    if (ok) perm[gbase[key] + r] = i;
}

// ---------- scatter edges into CSR (edges only — R5 form) ----------
__global__ void scatter_kernel(const int* __restrict__ src, const int* __restrict__ dst,
                               int* __restrict__ cursor, int* __restrict__ csr_src, int n) {
    int i = blockIdx.x * blockDim.x + threadIdx.x;
    if (i < n) {
        int d = dst[i];
        int pos = atomicAdd(&cursor[d], 1);
        csr_src[pos] = src[i];
    }
}

// ---------- MFMA GEMM: S = h @ W_self^T ; packed[n][c] = (bf16(exp(S)), bf16(h)) ----------
__global__ __launch_bounds__(256) void gemm_kernel(
        const float* __restrict__ h, const unsigned short* __restrict__ Wb,
        unsigned int* __restrict__ packed) {
    __shared__ unsigned short At[32][LDS_PITCH];  // bf16(h) tile
    __shared__ unsigned short Et[32][LDS_PITCH];  // bf16(exp(S)) tile
    int tid = threadIdx.x;
    int w = tid >> 6, l = tid & 63;
    int m0 = blockIdx.x * 32;
    int n0 = w * 64;
    int lm = l & 15, lk = (l >> 4) * 8;

#pragma unroll
    for (int it = 0; it < 8; ++it) {
        int q = it * 256 + tid;
        int row = q >> 6;
        int c4 = (q & 63) * 4;
        float4 x = *(const float4*)(h + (size_t)(m0 + row) * EMB + c4);
        At[row][c4 + 0] = bf16r(x.x);
        At[row][c4 + 1] = bf16r(x.y);
        At[row][c4 + 2] = bf16r(x.z);
        At[row][c4 + 3] = bf16r(x.w);
    }
    __syncthreads();

    floatx4 acc[2][4];
#pragma unroll
    for (int mt = 0; mt < 2; ++mt)
#pragma unroll
        for (int nt = 0; nt < 4; ++nt) acc[mt][nt] = (floatx4){0.f, 0.f, 0.f, 0.f};

    const unsigned short* a0p = &At[lm][lk];
    const unsigned short* a1p = &At[16 + lm][lk];
    const unsigned short* bp = Wb + (size_t)(n0 + lm) * EMB + lk;

#pragma unroll
    for (int k0 = 0; k0 < EMB; k0 += 32) {
        short8 a0 = *(const short8*)(a0p + k0);
        short8 a1 = *(const short8*)(a1p + k0);
        short8 b0 = *(const short8*)(bp + k0);
        short8 b1 = *(const short8*)(bp + 16 * EMB + k0);
        short8 b2 = *(const short8*)(bp + 32 * EMB + k0);
        short8 b3 = *(const short8*)(bp + 48 * EMB + k0);
        acc[0][0] = __builtin_amdgcn_mfma_f32_16x16x32_bf16(a0, b0, acc[0][0], 0, 0, 0);
        acc[0][1] = __builtin_amdgcn_mfma_f32_16x16x32_bf16(a0, b1, acc[0][1], 0, 0, 0);
        acc[0][2] = __builtin_amdgcn_mfma_f32_16x16x32_bf16(a0, b2, acc[0][2], 0, 0, 0);
        acc[0][3] = __builtin_amdgcn_mfma_f32_16x16x32_bf16(a0, b3, acc[0][3], 0, 0, 0);
        acc[1][0] = __builtin_amdgcn_mfma_f32_16x16x32_bf16(a1, b0, acc[1][0], 0, 0, 0);
        acc[1][1] = __builtin_amdgcn_mfma_f32_16x16x32_bf16(a1, b1, acc[1][1], 0, 0, 0);
        acc[1][2] = __builtin_amdgcn_mfma_f32_16x16x32_bf16(a1, b2, acc[1][2], 0, 0, 0);
        acc[1][3] = __builtin_amdgcn_mfma_f32_16x16x32_bf16(a1, b3, acc[1][3], 0, 0, 0);
    }

    // E -> LDS in C/D layout (col = lane&15, row = (lane>>4)*4 + reg)
#pragma unroll
    for (int mt = 0; mt < 2; ++mt)
#pragma unroll
        for (int nt = 0; nt < 4; ++nt) {
            int col = n0 + nt * 16 + lm;
#pragma unroll
            for (int r = 0; r < 4; ++r) {
                int row = mt * 16 + (l >> 4) * 4 + r;
                Et[row][col] = bf16r(__expf(acc[mt][nt][r]));
            }
        }
    __syncthreads();

#pragma unroll
    for (int it = 0; it < 8; ++it) {
        int q = it * 256 + tid;
        int row = q >> 6;
        int c4 = (q & 63) * 4;
        uint4 o;
        o.x = (unsigned)Et[row][c4 + 0] | ((unsigned)At[row][c4 + 0] << 16);
        o.y = (unsigned)Et[row][c4 + 1] | ((unsigned)At[row][c4 + 1] << 16);
        o.z = (unsigned)Et[row][c4 + 2] | ((unsigned)At[row][c4 + 2] << 16);
        o.w = (unsigned)Et[row][c4 + 3] | ((unsigned)At[row][c4 + 3] << 16);
        *(uint4*)&packed[(size_t)(m0 + row) * EMB + c4] = o;
    }
}

// ---------- aggregate: one wave per node, degree-sorted static schedule ----------
#define PROC(p)                                                                  \
    {                                                                            \
        unsigned u;                                                              \
        float e, hv;                                                             \
        u = (p).x; e = __uint_as_float(u << 16);                                 \
        hv = __uint_as_float(u & 0xffff0000u); ss0 += e; a0 = fmaf(e, hv, a0);   \
        u = (p).y; e = __uint_as_float(u << 16);                                 \
        hv = __uint_as_float(u & 0xffff0000u); ss1 += e; a1 = fmaf(e, hv, a1);   \
        u = (p).z; e = __uint_as_float(u << 16);                                 \
        hv = __uint_as_float(u & 0xffff0000u); ss2 += e; a2 = fmaf(e, hv, a2);   \
        u = (p).w; e = __uint_as_float(u << 16);                                 \
        hv = __uint_as_float(u & 0xffff0000u); ss3 += e; a3 = fmaf(e, hv, a3);   \
    }

__global__ __launch_bounds__(256) void aggregate_kernel(
        const float* __restrict__ h, const uint4* __restrict__ packed,
        const int* __restrict__ row_start, const int* __restrict__ csr_src,
        const int* __restrict__ perm, float* __restrict__ out) {
    int w = threadIdx.x >> 6, l = threadIdx.x & 63;
    int node = perm[blockIdx.x * 4 + w];
    int start = row_start[node], end = row_start[node + 1];
    if (start == end) {  // zero in-degree: pass through h
        float4 v = *(const float4*)(h + (size_t)node * EMB + l * 4);
        *(float4*)(out + (size_t)node * EMB + l * 4) = v;
        return;
    }
    float ss0 = 0.f, ss1 = 0.f, ss2 = 0.f, ss3 = 0.f;
    float a0 = 0.f, a1 = 0.f, a2 = 0.f, a3 = 0.f;
    for (int base = start; base < end; base += 64) {
        int cnt = min(64, end - base);
        int sv = (l < cnt) ? csr_src[base + l] : 0;
        int i = 0;
        for (; i + 8 <= cnt; i += 8) {
            int s0 = __shfl(sv, i),     s1 = __shfl(sv, i + 1);
            int s2 = __shfl(sv, i + 2), s3 = __shfl(sv, i + 3);
            int s4 = __shfl(sv, i + 4), s5 = __shfl(sv, i + 5);
            int s6 = __shfl(sv, i + 6), s7 = __shfl(sv, i + 7);
            uint4 p0 = packed[(size_t)s0 * 64 + l];
            uint4 p1 = packed[(size_t)s1 * 64 + l];
            uint4 p2 = packed[(size_t)s2 * 64 + l];
            uint4 p3 = packed[(size_t)s3 * 64 + l];
            uint4 p4 = packed[(size_t)s4 * 64 + l];
            uint4 p5 = packed[(size_t)s5 * 64 + l];
            uint4 p6 = packed[(size_t)s6 * 64 + l];
            uint4 p7 = packed[(size_t)s7 * 64 + l];
            PROC(p0); PROC(p1); PROC(p2); PROC(p3);
            PROC(p4); PROC(p5); PROC(p6); PROC(p7);
        }
        for (; i + 4 <= cnt; i += 4) {
            int s0 = __shfl(sv, i),     s1 = __shfl(sv, i + 1);
            int s2 = __shfl(sv, i + 2), s3 = __shfl(sv, i + 3);
            uint4 p0 = packed[(size_t)s0 * 64 + l];
            uint4 p1 = packed[(size_t)s1 * 64 + l];
            uint4 p2 = packed[(size_t)s2 * 64 + l];
            uint4 p3 = packed[(size_t)s3 * 64 + l];
            PROC(p0); PROC(p1); PROC(p2); PROC(p3);
        }
        for (; i < cnt; ++i) {
            int s = __shfl(sv, i);
            uint4 p = packed[(size_t)s * 64 + l];
            PROC(p);
        }
    }
    float4 o;
    o.x = a0 / ss0; o.y = a1 / ss1; o.z = a2 / ss2; o.w = a3 / ss3;
    *(float4*)(out + (size_t)node * EMB + l * 4) = o;
}

// ---------- launch ----------
extern "C" void kernel_launch(void* const* d_in, const int* in_sizes, int n_in,
                              void* d_out, int out_size, void* d_ws, size_t ws_size,
                              hipStream_t stream) {
    const float* h      = (const float*)d_in[0];
    // W_nb (d_in[1]), b_nb (d_in[2]), b_self (d_in[4]) are mathematically
    // irrelevant: constant per (dst, channel) inside each softmax segment,
    // cancel exactly in alpha = e / seg_sum.
    const float* W_self = (const float*)d_in[3];
    const int*   src    = (const int*)d_in[5];
    const int*   dst    = (const int*)d_in[6];
    float* out = (float*)d_out;

    char* ws = (char*)d_ws;
    unsigned int* packed = (unsigned int*)ws;                 // [N,256] uint (E,h) pairs
    size_t off = (size_t)N_NODES * EMB * sizeof(unsigned int);
    unsigned short* Wb = (unsigned short*)(ws + off); off += (size_t)EMB * EMB * sizeof(unsigned short);
    int* deg       = (int*)(ws + off); off += (size_t)N_NODES * sizeof(int);
    int* hist      = (int*)(ws + off); off += 256 * sizeof(int);  // adjacent: one memset covers deg+hist
    int* hcur      = (int*)(ws + off); off += 256 * sizeof(int);
    int* row_start = (int*)(ws + off); off += (size_t)(N_NODES + 1) * sizeof(int);
    int* cursor    = (int*)(ws + off); off += (size_t)N_NODES * sizeof(int);
    int* perm      = (int*)(ws + off); off += (size_t)N_NODES * sizeof(int);
    int* csr_src   = (int*)(ws + off); off += (size_t)N_EDGES * sizeof(int);

    (void)hipMemsetAsync(deg, 0, ((size_t)N_NODES + 256) * sizeof(int), stream);

    prep_kernel<<<(N_EDGES + 255) / 256, 256, 0, stream>>>(W_self, dst, deg, Wb);
    csr_kernel<<<NUM_TILES, 256, 0, stream>>>(deg, row_start, cursor, hist);
    hscan_kernel<<<1, 256, 0, stream>>>(hist, hcur);
    perm_kernel<<<NUM_TILES, 256, 0, stream>>>(deg, hcur, perm);
    scatter_kernel<<<(N_EDGES + 255) / 256, 256, 0, stream>>>(src, dst, cursor, csr_src, N_EDGES);
    gemm_kernel<<<N_NODES / 32, 256, 0, stream>>>(h, Wb, packed);
    aggregate_kernel<<<N_NODES / 4, 256, 0, stream>>>(h, (const uint4*)packed, row_start,
                                                      csr_src, perm, out);
}

// Round 9
// 186.064 us; speedup vs baseline: 2.5656x; 1.0261x over previous
//
#include <hip/hip_runtime.h>
#include <math.h>

#define N_NODES 20000
#define N_EDGES 320000
#define EMB 256
#define NUM_TILES ((N_NODES + 255) / 256)  // 79
#define LDS_PITCH 264                      // 256 + 8 shorts: breaks bank-stride, keeps 16B align

typedef __attribute__((ext_vector_type(8))) short short8;
typedef __attribute__((ext_vector_type(4))) float floatx4;

__device__ __forceinline__ unsigned short bf16r(float x) {
    unsigned u = __float_as_uint(x);
    u += 0x7fffu + ((u >> 16) & 1u);
    return (unsigned short)(u >> 16);
}

// ---------- prep: count degrees + convert W_self to bf16 ----------
__global__ __launch_bounds__(256) void prep_kernel(
        const float* __restrict__ W, const int* __restrict__ dst,
        int* __restrict__ deg, unsigned short* __restrict__ Wb) {
    int gid = blockIdx.x * 256 + threadIdx.x;
    if (gid < N_EDGES) atomicAdd(&deg[dst[gid]], 1);
    if (gid < (EMB * EMB) / 8) {
        long off = (long)gid * 8;
        float4 x = *(const float4*)(W + off);
        float4 y = *(const float4*)(W + off + 4);
        uint4 o;
        o.x = (unsigned)bf16r(x.x) | ((unsigned)bf16r(x.y) << 16);
        o.y = (unsigned)bf16r(x.z) | ((unsigned)bf16r(x.w) << 16);
        o.z = (unsigned)bf16r(y.x) | ((unsigned)bf16r(y.y) << 16);
        o.w = (unsigned)bf16r(y.z) | ((unsigned)bf16r(y.w) << 16);
        *(uint4*)(Wb + off) = o;
    }
}

// ---------- CSR: fused scan ----------
__global__ __launch_bounds__(256) void csr_kernel(const int* __restrict__ deg,
                                                  int* __restrict__ row_start,
                                                  int* __restrict__ cursor) {
    __shared__ int red[256];
    __shared__ int sc[256];
    int b = blockIdx.x, t = threadIdx.x;
    int i = b * 256 + t;
    int v = (i < N_NODES) ? deg[i] : 0;
    int s = 0;
    for (int j = t; j < b * 256; j += 256) s += deg[j];
    red[t] = s;
    sc[t] = v;
    __syncthreads();
#pragma unroll
    for (int off = 128; off > 0; off >>= 1) {
        if (t < off) red[t] += red[t + off];
        __syncthreads();
    }
    int base = red[0];
#pragma unroll
    for (int off = 1; off < 256; off <<= 1) {
        int tmp = (t >= off) ? sc[t - off] : 0;
        __syncthreads();
        sc[t] += tmp;
        __syncthreads();
    }
    int excl = base + sc[t] - v;
    if (i < N_NODES) {
        row_start[i] = excl;
        cursor[i] = excl;
    }
    if (i == N_NODES - 1) row_start[N_NODES] = excl + v;
}

__global__ void scatter_kernel(const int* __restrict__ src, const int* __restrict__ dst,
                               int* __restrict__ cursor, int* __restrict__ csr_src, int n) {
    int i = blockIdx.x * blockDim.x + threadIdx.x;
    if (i < n) {
        int d = dst[i];
        int pos = atomicAdd(&cursor[d], 1);
        csr_src[pos] = src[i];
    }
}

// ---------- MFMA GEMM: S = h @ W_self^T ; packed[n][c] = (bf16(exp(S)), bf16(h)) ----------
__global__ __launch_bounds__(256) void gemm_kernel(
        const float* __restrict__ h, const unsigned short* __restrict__ Wb,
        unsigned int* __restrict__ packed) {
    __shared__ unsigned short At[32][LDS_PITCH];  // bf16(h) tile
    __shared__ unsigned short Et[32][LDS_PITCH];  // bf16(exp(S)) tile
    int tid = threadIdx.x;
    int w = tid >> 6, l = tid & 63;
    int m0 = blockIdx.x * 32;
    int n0 = w * 64;
    int lm = l & 15, lk = (l >> 4) * 8;

#pragma unroll
    for (int it = 0; it < 8; ++it) {
        int q = it * 256 + tid;
        int row = q >> 6;
        int c4 = (q & 63) * 4;
        float4 x = *(const float4*)(h + (size_t)(m0 + row) * EMB + c4);
        At[row][c4 + 0] = bf16r(x.x);
        At[row][c4 + 1] = bf16r(x.y);
        At[row][c4 + 2] = bf16r(x.z);
        At[row][c4 + 3] = bf16r(x.w);
    }
    __syncthreads();

    floatx4 acc[2][4];
#pragma unroll
    for (int mt = 0; mt < 2; ++mt)
#pragma unroll
        for (int nt = 0; nt < 4; ++nt) acc[mt][nt] = (floatx4){0.f, 0.f, 0.f, 0.f};

    const unsigned short* a0p = &At[lm][lk];
    const unsigned short* a1p = &At[16 + lm][lk];
    const unsigned short* bp = Wb + (size_t)(n0 + lm) * EMB + lk;

#pragma unroll
    for (int k0 = 0; k0 < EMB; k0 += 32) {
        short8 a0 = *(const short8*)(a0p + k0);
        short8 a1 = *(const short8*)(a1p + k0);
        short8 b0 = *(const short8*)(bp + k0);
        short8 b1 = *(const short8*)(bp + 16 * EMB + k0);
        short8 b2 = *(const short8*)(bp + 32 * EMB + k0);
        short8 b3 = *(const short8*)(bp + 48 * EMB + k0);
        acc[0][0] = __builtin_amdgcn_mfma_f32_16x16x32_bf16(a0, b0, acc[0][0], 0, 0, 0);
        acc[0][1] = __builtin_amdgcn_mfma_f32_16x16x32_bf16(a0, b1, acc[0][1], 0, 0, 0);
        acc[0][2] = __builtin_amdgcn_mfma_f32_16x16x32_bf16(a0, b2, acc[0][2], 0, 0, 0);
        acc[0][3] = __builtin_amdgcn_mfma_f32_16x16x32_bf16(a0, b3, acc[0][3], 0, 0, 0);
        acc[1][0] = __builtin_amdgcn_mfma_f32_16x16x32_bf16(a1, b0, acc[1][0], 0, 0, 0);
        acc[1][1] = __builtin_amdgcn_mfma_f32_16x16x32_bf16(a1, b1, acc[1][1], 0, 0, 0);
        acc[1][2] = __builtin_amdgcn_mfma_f32_16x16x32_bf16(a1, b2, acc[1][2], 0, 0, 0);
        acc[1][3] = __builtin_amdgcn_mfma_f32_16x16x32_bf16(a1, b3, acc[1][3], 0, 0, 0);
    }

    // E -> LDS in C/D layout (col = lane&15, row = (lane>>4)*4 + reg)
#pragma unroll
    for (int mt = 0; mt < 2; ++mt)
#pragma unroll
        for (int nt = 0; nt < 4; ++nt) {
            int col = n0 + nt * 16 + lm;
#pragma unroll
            for (int r = 0; r < 4; ++r) {
                int row = mt * 16 + (l >> 4) * 4 + r;
                Et[row][col] = bf16r(__expf(acc[mt][nt][r]));
            }
        }
    __syncthreads();

#pragma unroll
    for (int it = 0; it < 8; ++it) {
        int q = it * 256 + tid;
        int row = q >> 6;
        int c4 = (q & 63) * 4;
        uint4 o;
        o.x = (unsigned)Et[row][c4 + 0] | ((unsigned)At[row][c4 + 0] << 16);
        o.y = (unsigned)Et[row][c4 + 1] | ((unsigned)At[row][c4 + 1] << 16);
        o.z = (unsigned)Et[row][c4 + 2] | ((unsigned)At[row][c4 + 2] << 16);
        o.w = (unsigned)Et[row][c4 + 3] | ((unsigned)At[row][c4 + 3] << 16);
        *(uint4*)&packed[(size_t)(m0 + row) * EMB + c4] = o;
    }
}

// ---------- aggregate: one wave per node; 16-deep predicated gather pipeline ----------
// wt = 0/1 validity: multiplying e kills both the denominator and numerator
// contribution of padded slots, so every node runs ceil(deg/16) fully
// parallel batches with no serial remainder chain.
#define PROCW(p, wt)                                                             \
    {                                                                            \
        unsigned u;                                                              \
        float e, hv;                                                             \
        u = (p).x; e = __uint_as_float(u << 16) * (wt);                          \
        hv = __uint_as_float(u & 0xffff0000u); ss0 += e; a0 = fmaf(e, hv, a0);   \
        u = (p).y; e = __uint_as_float(u << 16) * (wt);                          \
        hv = __uint_as_float(u & 0xffff0000u); ss1 += e; a1 = fmaf(e, hv, a1);   \
        u = (p).z; e = __uint_as_float(u << 16) * (wt);                          \
        hv = __uint_as_float(u & 0xffff0000u); ss2 += e; a2 = fmaf(e, hv, a2);   \
        u = (p).w; e = __uint_as_float(u << 16) * (wt);                          \
        hv = __uint_as_float(u & 0xffff0000u); ss3 += e; a3 = fmaf(e, hv, a3);   \
    }

__global__ __launch_bounds__(256) void aggregate_kernel(
        const float* __restrict__ h, const uint4* __restrict__ packed,
        const int* __restrict__ row_start, const int* __restrict__ csr_src,
        float* __restrict__ out) {
    int w = threadIdx.x >> 6, l = threadIdx.x & 63;
    int node = blockIdx.x * 4 + w;
    int start = row_start[node], end = row_start[node + 1];
    if (start == end) {  // zero in-degree: pass through h
        float4 v = *(const float4*)(h + (size_t)node * EMB + l * 4);
        *(float4*)(out + (size_t)node * EMB + l * 4) = v;
        return;
    }
    float ss0 = 0.f, ss1 = 0.f, ss2 = 0.f, ss3 = 0.f;
    float a0 = 0.f, a1 = 0.f, a2 = 0.f, a3 = 0.f;
    for (int base = start; base < end; base += 64) {
        int cnt = min(64, end - base);
        int sv = csr_src[base + min(l, cnt - 1)];  // clamped: always valid
        for (int i = 0; i < cnt; i += 16) {
            uint4 p[16];
            float wt[16];
#pragma unroll
            for (int j = 0; j < 16; ++j) {
                int idx = i + j;
                int s = __shfl(sv, min(idx, cnt - 1));
                p[j] = packed[(size_t)s * 64 + l];
                wt[j] = (idx < cnt) ? 1.f : 0.f;
            }
#pragma unroll
            for (int j = 0; j < 16; ++j) PROCW(p[j], wt[j]);
        }
    }
    float4 o;
    o.x = a0 / ss0; o.y = a1 / ss1; o.z = a2 / ss2; o.w = a3 / ss3;
    *(float4*)(out + (size_t)node * EMB + l * 4) = o;
}

// ---------- launch ----------
extern "C" void kernel_launch(void* const* d_in, const int* in_sizes, int n_in,
                              void* d_out, int out_size, void* d_ws, size_t ws_size,
                              hipStream_t stream) {
    const float* h      = (const float*)d_in[0];
    // W_nb (d_in[1]), b_nb (d_in[2]), b_self (d_in[4]) are mathematically
    // irrelevant: constant per (dst, channel) inside each softmax segment,
    // cancel exactly in alpha = e / seg_sum.
    const float* W_self = (const float*)d_in[3];
    const int*   src    = (const int*)d_in[5];
    const int*   dst    = (const int*)d_in[6];
    float* out = (float*)d_out;

    char* ws = (char*)d_ws;
    unsigned int* packed = (unsigned int*)ws;                 // [N,256] uint (E,h) pairs
    size_t off = (size_t)N_NODES * EMB * sizeof(unsigned int);
    unsigned short* Wb = (unsigned short*)(ws + off); off += (size_t)EMB * EMB * sizeof(unsigned short);
    int* deg       = (int*)(ws + off); off += (size_t)N_NODES * sizeof(int);
    int* row_start = (int*)(ws + off); off += (size_t)(N_NODES + 1) * sizeof(int);
    int* cursor    = (int*)(ws + off); off += (size_t)N_NODES * sizeof(int);
    int* csr_src   = (int*)(ws + off); off += (size_t)N_EDGES * sizeof(int);

    (void)hipMemsetAsync(deg, 0, (size_t)N_NODES * sizeof(int), stream);

    prep_kernel<<<(N_EDGES + 255) / 256, 256, 0, stream>>>(W_self, dst, deg, Wb);
    csr_kernel<<<NUM_TILES, 256, 0, stream>>>(deg, row_start, cursor);
    scatter_kernel<<<(N_EDGES + 255) / 256, 256, 0, stream>>>(src, dst, cursor, csr_src, N_EDGES);
    gemm_kernel<<<N_NODES / 32, 256, 0, stream>>>(h, Wb, packed);
    aggregate_kernel<<<N_NODES / 4, 256, 0, stream>>>(h, (const uint4*)packed, row_start,
                                                      csr_src, out);
}